// Round 3
// baseline (176.644 us; speedup 1.0000x reference)
//
#include <hip/hip_runtime.h>
#include <stdint.h>

#define NN 2048
#define LL 21
#define CAP 200
#define TOT (LL * CAP)
#define TMAX 320                 // matrix-resolve candidate window (5 chunks of 64)
#define NCH (TMAX / 64)
#define NBK 1024                 // score buckets

typedef unsigned long long u64;
typedef unsigned int u32;

// ---------------- shared-memory layout (single 54.5 KB arena) ----------------
// Phase 1: [0,21504) float tile ; [21504,37888) skey ; [37888,54272) skey2
// Phase 2: [0,4096) histR ; [4096,8192) cursor ; [8192,12288) dstart ; skey,skey2 live
// Phase 3: [0,5120) cbox[320] ; [5120,7680) R rows ; [7680,12800) T blocks ;
//          [12800,16000) kept[200] ; skey2 lives
// Phase 4 (winner): [0,33600) keys ; [33600,37696) histR ; [37696,41792) cursor ;
//          [41792,45888) dstart ; [45888,54080) arr[1024]
#define SMEM_BYTES 54272

__device__ __forceinline__ u64 shfl_u64(u64 v, int lane) {
    int lo = (int)(u32)(v & 0xFFFFFFFFull);
    int hi = (int)(u32)(v >> 32);
    lo = __shfl(lo, lane);
    hi = __shfl(hi, lane);
    return ((u64)(u32)hi << 32) | (u32)lo;
}

__device__ __forceinline__ float4 clip01(float4 b) {
    b.x = fminf(fmaxf(b.x, 0.0f), 1.0f);
    b.y = fminf(fmaxf(b.y, 0.0f), 1.0f);
    b.z = fminf(fmaxf(b.z, 0.0f), 1.0f);
    b.w = fminf(fmaxf(b.w, 0.0f), 1.0f);
    return b;
}

// decode, exact np op order (absmax 0.0 in R1/R2)
__device__ __forceinline__ float4 decode_box(const float4 roi, const float4 dd) {
#pragma clang fp contract(off)
    float h  = roi.z - roi.x;
    float w  = roi.w - roi.y;
    float cy = roi.x + 0.5f * h;
    float cx = roi.y + 0.5f * w;
    float d0 = dd.x * 0.1f;
    float d1 = dd.y * 0.1f;
    float d2 = dd.z * 0.2f;
    float d3 = dd.w * 0.2f;
    float nh = (float)exp((double)d2) * h;
    float nw = (float)exp((double)d3) * w;
    float ncy = d0 * h + cy;
    float ncx = d1 * w + cx;
    return make_float4(ncy - 0.5f * nh, ncx - 0.5f * nw, ncy + 0.5f * nh, ncx + 0.5f * nw);
}

__device__ __forceinline__ bool iou_gt(const float4 a, const float4 b) {
#pragma clang fp contract(off)
    float areaA = (a.z - a.x) * (a.w - a.y);
    float areaB = (b.z - b.x) * (b.w - b.y);
    float ih = fminf(a.z, b.z) - fmaxf(a.x, b.x);
    ih = fmaxf(ih, 0.0f);
    float iw = fminf(a.w, b.w) - fmaxf(a.y, b.y);
    iw = fmaxf(iw, 0.0f);
    float inter = ih * iw;
    float denom = ((areaA + areaB) - inter) + 1e-9f;
    return (inter / denom) > 0.5f;
}

// reverse-bucket of a key: rb=0 is the HIGHEST score bucket (desc order)
__device__ __forceinline__ int rb_of(u64 key) {
    u32 sb = (u32)(key >> 32);                 // score bits, in (0x3F000000, 0x3F800000)
    int rb = 1023 - (int)((sb - 0x3F000000u) >> 13);
    return min(max(rb, 0), 1023);
}

__device__ __forceinline__ u64 lowmask(int n) {   // n in [0,64]
    return (n >= 64) ? ~0ull : ((1ull << n) - 1ull);
}

// descending-order exclusive scan of histR[1024] -> dstart & cursor (both = starts)
__device__ void desc_scan(int* histR, int* dstart, int* cursor, int* wtot, int t) {
    const int lane = t & 63, w = t >> 6;
    int c[4], local = 0;
    for (int k = 0; k < 4; ++k) { c[k] = histR[4 * t + k]; local += c[k]; }
    int incl = local;
    for (int d = 1; d < 64; d <<= 1) {
        int v = __shfl_up(incl, d);
        if (lane >= d) incl += v;
    }
    if (lane == 63) wtot[w] = incl;
    __syncthreads();
    int woff = 0;
    for (int i = 0; i < w; ++i) woff += wtot[i];
    int run = woff + incl - local;   // exclusive prefix for this thread's 4 buckets
    for (int k = 0; k < 4; ++k) {
        dstart[4 * t + k] = run;
        cursor[4 * t + k] = run;
        run += c[k];
    }
    __syncthreads();
}

__global__ __launch_bounds__(256) void fused_kernel(
    const float* __restrict__ roi,      // (N,4)
    const float* __restrict__ deltas,   // (N, L*4)
    const float* __restrict__ probs,    // (N, L)
    u64* __restrict__ cand_key,         // (L*CAP)
    float4* __restrict__ cand_box,      // (L*CAP)
    u64* __restrict__ fb_key,           // (L)
    float4* __restrict__ fb_box,        // (L)
    int* __restrict__ ctr,              // zeroed by memset before launch
    float* __restrict__ out)            // [800 boxes][200 labels][200 scores]
{
    const int cls = blockIdx.x;
    const int t = threadIdx.x;

    __shared__ char smem_raw[SMEM_BYTES];
    char* sm = smem_raw;
    __shared__ int sCnt, sK, sLast, sRbstar;
    __shared__ u64 sGmax;
    __shared__ u64 keepm[NCH];
    __shared__ int wtot[4];

    if (t == 0) { sCnt = 0; sK = 0; sGmax = 0ull; }
    for (int s = t; s < CAP; s += 256) cand_key[cls * CAP + s] = 0ull;
    __syncthreads();

    // ---------------- Phase 1: argmax + score keys + compaction ----------------
    {
        float* tile = (float*)sm;                      // 256*21 floats
        u64* skey = (u64*)(sm + 21504);
        const u64 THRKEY = ((u64)0x3F000000u << 32) | 0xFFFFFFFFull;  // strict > 0.5
        u64 lq[8];
        int ln = 0;
        u64 lmax = 0ull;
        for (int t8 = 0; t8 < 8; ++t8) {
            const float4* src = (const float4*)(probs) + t8 * 1344;
            float4* dst = (float4*)tile;
            for (int i = t; i < 1344; i += 256) dst[i] = src[i];
            __syncthreads();
            const float* row = tile + t * LL;          // stride 21 (odd): conflict-free
            float best = row[0];
            int bi = 0;
            for (int j = 1; j < LL; ++j) {
                float v = row[j];
                if (v > best) { best = v; bi = j; }
            }
            float sc = (bi != 0) ? row[cls] : 0.0f;
            u64 key = ((u64)__float_as_uint(sc) << 32) | (u32)(~(u32)(t8 * 256 + t));
            if (key > lmax) lmax = key;
            if (key > THRKEY) lq[ln++] = key;
            __syncthreads();                           // tile reused next iter
        }
        atomicMax(&sGmax, lmax);
        int wbase = atomicAdd(&sCnt, ln);
        for (int j = 0; j < ln; ++j) skey[wbase + j] = lq[j];
        __syncthreads();
    }
    const int M = sCnt;

    // per-class fallback rank-0 box (always kept)
    if (t == 0) {
        u64 g = sGmax;
        u32 a0 = ~(u32)(g & 0xFFFFFFFFull);
        float4 rb = *(const float4*)(roi + a0 * 4);
        float4 dd = *(const float4*)(deltas + a0 * (LL * 4) + cls * 4);
        fb_box[cls] = decode_box(rb, dd);
        fb_key[cls] = (g & 0xFFFFFFFF00000000ull) | (u32)(~(u32)(cls * NN));
    }

    // ---------------- Phase 2: exact bucket sort (descending) ----------------
    {
        int* histR  = (int*)sm;
        int* cursor = (int*)(sm + 4096);
        int* dstart = (int*)(sm + 8192);
        u64* skey   = (u64*)(sm + 21504);
        u64* skey2  = (u64*)(sm + 37888);
        for (int i = t; i < NBK; i += 256) histR[i] = 0;
        __syncthreads();
        for (int i = t; i < M; i += 256) atomicAdd(&histR[rb_of(skey[i])], 1);
        __syncthreads();
        desc_scan(histR, dstart, cursor, wtot, t);
        for (int i = t; i < M; i += 256) {
            u64 k = skey[i];
            int pos = atomicAdd(&cursor[rb_of(k)], 1);
            skey2[pos] = k;
        }
        __syncthreads();
        for (int rb = t; rb < NBK; rb += 256) {
            int s = dstart[rb], len = histR[rb];
            for (int a = s + 1; a < s + len; ++a) {     // insertion sort desc
                u64 v = skey2[a];
                int b = a;
                while (b > s && skey2[b - 1] < v) { skey2[b] = skey2[b - 1]; --b; }
                skey2[b] = v;
            }
        }
        __syncthreads();
    }

    // ---------------- Phase 3: matrix NMS over top-TMAX ----------------
    {
        float4* cbox = (float4*)sm;                    // [TMAX]
        u64* R  = (u64*)(sm + 5120);                   // [NCH*64] intra rows
        u64* Tm = (u64*)(sm + 7680);                   // [10*64] transposed ext blocks
        float4* kept = (float4*)(sm + 12800);          // [CAP]
        u64* skey2 = (u64*)(sm + 37888);

        const int TT = min(M, TMAX);
        const int NCHe = (TT + 63) / 64;

        for (int r = t; r < TT; r += 256) {
            u32 a = ~(u32)(skey2[r] & 0xFFFFFFFFull);
            float4 rbx = *(const float4*)(roi + a * 4);
            float4 dd = *(const float4*)(deltas + a * (LL * 4) + cls * 4);
            cbox[r] = decode_box(rbx, dd);
        }
        __syncthreads();

        // build pair-bit matrix (parallel, pipelined)
        for (int task = t; task < NCHe * 64; task += 256) {
            const int cj = task >> 6, j = task & 63;
            const int gj = cj * 64 + j;
            const bool valid = (gj < TT);
            float4 bj;
            if (valid) bj = cbox[gj];
            u64 row = 0ull;
            if (valid) {
                const int nb = min(64, TT - cj * 64);
                for (int r2 = j + 1; r2 < nb; ++r2)
                    if (iou_gt(bj, cbox[cj * 64 + r2])) row |= (1ull << r2);
            }
            R[cj * 64 + j] = row;
            for (int ci = 0; ci < cj; ++ci) {
                u64 wd = 0ull;
                if (valid) {
                    const float4* cb = cbox + ci * 64;
                    for (int i = 0; i < 64; ++i)
                        if (iou_gt(cb[i], bj)) wd |= (1ull << i);
                }
                Tm[(cj * (cj - 1) / 2 + ci) * 64 + j] = wd;
            }
        }
        __syncthreads();

        // wave0: barrier-free resolve across chunks with sparse skip-list
        if (t < 64) {
            int K = 0;
            for (int cj = 0; cj < NCHe; ++cj) {
                if (K >= CAP) break;
                const int nb = min(64, TT - cj * 64);
                u64 row = R[cj * 64 + t];
                bool ext = (t >= nb);
                for (int ci = 0; ci < cj; ++ci)
                    if (Tm[(cj * (cj - 1) / 2 + ci) * 64 + t] & keepm[ci]) ext = true;
                u64 rem = __ballot(ext);
                const u64 nz = __ballot(row != 0ull) & ~rem;
                u64 m = nz;
                while (m) {
                    int i = __ffsll(m) - 1;
                    u64 ri = shfl_u64(row, i);
                    rem |= ri;
                    u64 gt = (i == 63) ? 0ull : ~lowmask(i + 1);
                    m = nz & ~rem & gt;
                }
                u64 keep = ~rem & lowmask(nb);
                if (t == 0) keepm[cj] = keep;
                if (t < nb && ((keep >> t) & 1ull)) {
                    int krank = K + __popcll(keep & lowmask(t));
                    if (krank < CAP) {
                        kept[krank] = cbox[cj * 64 + t];
                        int slot = cls * CAP + krank;
                        cand_key[slot] = (skey2[cj * 64 + t] & 0xFFFFFFFF00000000ull) |
                                         (u32)(~(u32)slot);
                        cand_box[slot] = cbox[cj * 64 + t];
                    }
                }
                K += __popcll(keep);
            }
            if (t == 0) sK = K;
        }
        __syncthreads();

        // rare fallback: continue chunked NMS past TMAX (exact, R2-style)
        int K = sK;
        if (K < CAP && M > TT) {
            u64* sup = (u64*)(sm + 5120);              // reuse R region: [4][64]
            unsigned char* extq = (unsigned char*)(sm + 7680);  // [4][64]
            const int q = t >> 6, r = t & 63;
            for (int base = TT; base < M; base += 64) {
                K = sK;
                if (K >= CAP) break;
                const int nb = min(64, M - base);
                if (t < nb) {
                    u32 a = ~(u32)(skey2[base + t] & 0xFFFFFFFFull);
                    float4 rbx = *(const float4*)(roi + a * 4);
                    float4 dd = *(const float4*)(deltas + a * (LL * 4) + cls * 4);
                    cbox[t] = decode_box(rbx, dd);
                }
                __syncthreads();
                u64 bits = 0ull;
                if (r < nb) {
                    float4 br = cbox[r];
                    int lo = max(r + 1, q * 16), hi = min(nb, (q + 1) * 16);
                    for (int r2 = lo; r2 < hi; ++r2)
                        if (iou_gt(br, cbox[r2])) bits |= (1ull << r2);
                }
                sup[q * 64 + r] = bits;
                bool f = false;
                if (r < nb) {
                    float4 bm = cbox[r];
                    int per = (K + 3) >> 2;
                    int e0 = q * per, e1 = min(K, e0 + per);
                    for (int e = e0; e < e1; ++e)
                        if (iou_gt(kept[e], bm)) { f = true; break; }
                }
                extq[q * 64 + r] = f ? 1 : 0;
                __syncthreads();
                if (t < 64) {
                    u64 row = sup[t] | sup[64 + t] | sup[128 + t] | sup[192 + t];
                    bool ext = (t < nb) ? ((extq[t] | extq[64 + t] | extq[128 + t] |
                                            extq[192 + t]) != 0) : true;
                    u64 rem = __ballot(ext);
                    const u64 nz = __ballot(row != 0ull) & ~rem;
                    u64 m = nz;
                    while (m) {
                        int i = __ffsll(m) - 1;
                        u64 ri = shfl_u64(row, i);
                        rem |= ri;
                        u64 gt = (i == 63) ? 0ull : ~lowmask(i + 1);
                        m = nz & ~rem & gt;
                    }
                    u64 keep = ~rem & lowmask(nb);
                    if (t < nb && ((keep >> t) & 1ull)) {
                        int krank = K + __popcll(keep & lowmask(t));
                        if (krank < CAP) {
                            kept[krank] = cbox[t];
                            int slot = cls * CAP + krank;
                            cand_key[slot] = (skey2[base + t] & 0xFFFFFFFF00000000ull) |
                                             (u32)(~(u32)slot);
                            cand_box[slot] = cbox[t];
                        }
                    }
                    if (t == 0) sK = K + __popcll(keep);
                }
                __syncthreads();
            }
        }
    }

    // ---------------- Phase 4: last block does global top-200 ----------------
    __threadfence();   // agent-scope release of cand/fb writes
    if (t == 0) {
        int old = __hip_atomic_fetch_add(ctr, 1, __ATOMIC_ACQ_REL, __HIP_MEMORY_SCOPE_AGENT);
        sLast = (old == LL - 1) ? 1 : 0;
        sRbstar = 1023;
    }
    __syncthreads();
    if (!sLast) return;

    {
        u64* keys   = (u64*)sm;                        // [TOT]
        int* histR  = (int*)(sm + 33600);
        int* cursor = (int*)(sm + 37696);
        int* dstart = (int*)(sm + 41792);
        u64* arr    = (u64*)(sm + 45888);              // [1024]

        for (int i = t; i < NBK; i += 256) histR[i] = 0;
        for (int i = t; i < 1024; i += 256) arr[i] = 0ull;
        __syncthreads();
        for (int i = t; i < TOT; i += 256) {
            u64 k = __hip_atomic_load(&cand_key[i], __ATOMIC_RELAXED,
                                      __HIP_MEMORY_SCOPE_AGENT);
            keys[i] = k;
            if (k != 0ull) atomicAdd(&histR[rb_of(k)], 1);
        }
        __syncthreads();
        desc_scan(histR, dstart, cursor, wtot, t);
        // threshold bucket: smallest rb with dstart+len >= CAP (or last nonempty)
        for (int k = 0; k < 4; ++k) {
            int rb = 4 * t + k;
            if (dstart[rb] + histR[rb] >= CAP) atomicMin(&sRbstar, rb);
        }
        __syncthreads();
        const int rbstar = sRbstar;
        for (int i = t; i < TOT; i += 256) {
            u64 k = keys[i];
            if (k != 0ull) {
                int rb = rb_of(k);
                if (rb <= rbstar) {
                    int pos = atomicAdd(&cursor[rb], 1);
                    if (pos < 1024) arr[pos] = k;
                }
            }
        }
        __syncthreads();
        for (int rb = t; rb <= rbstar; rb += 256) {
            int s = dstart[rb], len = histR[rb];
            int e = min(s + len, 1024);
            for (int a = s + 1; a < e; ++a) {
                u64 v = arr[a];
                int b = a;
                while (b > s && arr[b - 1] < v) { arr[b] = arr[b - 1]; --b; }
                arr[b] = v;
            }
        }
        __syncthreads();

        for (int o = t; o < CAP; o += 256) {
            u64 key = arr[o];
            float4 b = make_float4(0.0f, 0.0f, 0.0f, 0.0f);
            float lab = 0.0f, sc = 0.0f;
            if (key != 0ull) {
                u32 slot = ~(u32)(key & 0xFFFFFFFFull);
                sc = __uint_as_float((u32)(key >> 32));
                lab = (float)(slot / CAP);
                const u64* bp = (const u64*)&cand_box[slot];
                u64 w0 = __hip_atomic_load(bp,     __ATOMIC_RELAXED, __HIP_MEMORY_SCOPE_AGENT);
                u64 w1 = __hip_atomic_load(bp + 1, __ATOMIC_RELAXED, __HIP_MEMORY_SCOPE_AGENT);
                float4 bb;
                ((u64*)&bb)[0] = w0;
                ((u64*)&bb)[1] = w1;
                b = clip01(bb);
            }
            out[o * 4 + 0] = b.x;
            out[o * 4 + 1] = b.y;
            out[o * 4 + 2] = b.z;
            out[o * 4 + 3] = b.w;
            out[4 * CAP + o] = lab;
            out[5 * CAP + o] = sc;
        }
        __syncthreads();

        if (t == 0 && arr[0] == 0ull) {   // no candidate anywhere -> fallback box
            u64 best = 0ull;
            int bc = 0;
            for (int c = 0; c < LL; ++c) {
                u64 k = __hip_atomic_load(&fb_key[c], __ATOMIC_RELAXED,
                                          __HIP_MEMORY_SCOPE_AGENT);
                if (k > best) { best = k; bc = c; }
            }
            float bs = __uint_as_float((u32)(best >> 32));
            if (bs >= 0.001f) {
                const u64* bp = (const u64*)&fb_box[bc];
                u64 w0 = __hip_atomic_load(bp,     __ATOMIC_RELAXED, __HIP_MEMORY_SCOPE_AGENT);
                u64 w1 = __hip_atomic_load(bp + 1, __ATOMIC_RELAXED, __HIP_MEMORY_SCOPE_AGENT);
                float4 bb;
                ((u64*)&bb)[0] = w0;
                ((u64*)&bb)[1] = w1;
                bb = clip01(bb);
                out[0] = bb.x; out[1] = bb.y; out[2] = bb.z; out[3] = bb.w;
                out[4 * CAP] = (float)bc;
                out[5 * CAP] = bs;
            }
        }
    }
}

extern "C" void kernel_launch(void* const* d_in, const int* in_sizes, int n_in,
                              void* d_out, int out_size, void* d_ws, size_t ws_size,
                              hipStream_t stream) {
    const float* roi    = (const float*)d_in[0];   // (1,2048,4)
    const float* deltas = (const float*)d_in[1];   // (1,2048,84)
    const float* probs  = (const float*)d_in[2];   // (1,2048,21)
    float* out = (float*)d_out;

    char* ws = (char*)d_ws;
    u64*    cand_key = (u64*)ws;                   // 4200*8  = 33600
    float4* cand_box = (float4*)(ws + 33600);      // 4200*16 = 67200 -> 100800
    u64*    fb_key   = (u64*)(ws + 100800);        // 168 -> 100968 (pad to 100976)
    float4* fb_box   = (float4*)(ws + 100976);     // 336 -> 101312
    int*    ctr      = (int*)(ws + 101312);

    hipMemsetAsync(ctr, 0, 4, stream);
    fused_kernel<<<LL, 256, 0, stream>>>(roi, deltas, probs,
                                         cand_key, cand_box, fb_key, fb_box, ctr, out);
}

// Round 4
// 150.083 us; speedup vs baseline: 1.1770x; 1.1770x over previous
//
#include <hip/hip_runtime.h>
#include <stdint.h>

#define NN 2048
#define LL 21
#define CAP 200
#define TOT (LL * CAP)
#define TMAX 320                 // matrix-resolve candidate window (5 chunks of 64)
#define NCH (TMAX / 64)
#define NBK 1024                 // score buckets

typedef unsigned long long u64;
typedef unsigned int u32;

__device__ __forceinline__ u64 shfl_u64(u64 v, int lane) {
    int lo = (int)(u32)(v & 0xFFFFFFFFull);
    int hi = (int)(u32)(v >> 32);
    lo = __shfl(lo, lane);
    hi = __shfl(hi, lane);
    return ((u64)(u32)hi << 32) | (u32)lo;
}

__device__ __forceinline__ float4 clip01(float4 b) {
    b.x = fminf(fmaxf(b.x, 0.0f), 1.0f);
    b.y = fminf(fmaxf(b.y, 0.0f), 1.0f);
    b.z = fminf(fmaxf(b.z, 0.0f), 1.0f);
    b.w = fminf(fmaxf(b.w, 0.0f), 1.0f);
    return b;
}

// decode, exact np op order (absmax 0.0 in R1-R3)
__device__ __forceinline__ float4 decode_box(const float4 roi, const float4 dd) {
#pragma clang fp contract(off)
    float h  = roi.z - roi.x;
    float w  = roi.w - roi.y;
    float cy = roi.x + 0.5f * h;
    float cx = roi.y + 0.5f * w;
    float d0 = dd.x * 0.1f;
    float d1 = dd.y * 0.1f;
    float d2 = dd.z * 0.2f;
    float d3 = dd.w * 0.2f;
    float nh = (float)exp((double)d2) * h;
    float nw = (float)exp((double)d3) * w;
    float ncy = d0 * h + cy;
    float ncx = d1 * w + cx;
    return make_float4(ncy - 0.5f * nh, ncx - 0.5f * nw, ncy + 0.5f * nh, ncx + 0.5f * nw);
}

__device__ __forceinline__ bool iou_gt(const float4 a, const float4 b) {
#pragma clang fp contract(off)
    float areaA = (a.z - a.x) * (a.w - a.y);
    float areaB = (b.z - b.x) * (b.w - b.y);
    float ih = fminf(a.z, b.z) - fmaxf(a.x, b.x);
    ih = fmaxf(ih, 0.0f);
    float iw = fminf(a.w, b.w) - fmaxf(a.y, b.y);
    iw = fmaxf(iw, 0.0f);
    float inter = ih * iw;
    float denom = ((areaA + areaB) - inter) + 1e-9f;
    return (inter / denom) > 0.5f;
}

// reverse-bucket of a key: rb=0 is the HIGHEST score bucket (desc order)
__device__ __forceinline__ int rb_of(u64 key) {
    u32 sb = (u32)(key >> 32);                 // score bits in (0x3F000000, 0x3F800000)
    int rb = 1023 - (int)((sb - 0x3F000000u) >> 13);
    return min(max(rb, 0), 1023);
}

__device__ __forceinline__ u64 lowmask(int n) {   // n in [0,64]
    return (n >= 64) ? ~0ull : ((1ull << n) - 1ull);
}

// descending-order exclusive scan of histR[1024] -> dstart & cursor (both = starts)
__device__ void desc_scan(int* histR, int* dstart, int* cursor, int* wtot, int t) {
    const int lane = t & 63, w = t >> 6;
    int c[4], local = 0;
    for (int k = 0; k < 4; ++k) { c[k] = histR[4 * t + k]; local += c[k]; }
    int incl = local;
    for (int d = 1; d < 64; d <<= 1) {
        int v = __shfl_up(incl, d);
        if (lane >= d) incl += v;
    }
    if (lane == 63) wtot[w] = incl;
    __syncthreads();
    int woff = 0;
    for (int i = 0; i < w; ++i) woff += wtot[i];
    int run = woff + incl - local;
    for (int k = 0; k < 4; ++k) {
        dstart[4 * t + k] = run;
        cursor[4 * t + k] = run;
        run += c[k];
    }
    __syncthreads();
}

// ---------------- Kernel A: grid-parallel argmax + score bits ----------------
__global__ __launch_bounds__(256) void score_kernel(
    const float* __restrict__ probs,   // (N, L)
    u32* __restrict__ scoreT)          // (L, N) score bits (0 if background)
{
    __shared__ float tile[256 * LL];
    const int a0 = blockIdx.x * 256;
    const int t = threadIdx.x;
    const float4* src = (const float4*)probs + blockIdx.x * 1344;
    float4* dst = (float4*)tile;
    for (int i = t; i < 1344; i += 256) dst[i] = src[i];
    __syncthreads();
    const float* row = tile + t * LL;   // stride 21 (odd): 2-way max, free
    float best = row[0];
    int bi = 0;
    for (int j = 1; j < LL; ++j) {
        float v = row[j];
        if (v > best) { best = v; bi = j; }
    }
    for (int c = 0; c < LL; ++c)
        scoreT[c * NN + a0 + t] = (bi != 0) ? __float_as_uint(row[c]) : 0u;  // coalesced
}

// ---------------- Kernel B: per-class sort + matrix NMS ----------------
// Arena: [0,16384) skey -> (cbox 5120 | R 2560 | Tm 5120 | kept 3200)
//        [16384,32768) skey2 ; [32768,45056) histR/cursor/dstart
#define SMEM_B 45056

__global__ __launch_bounds__(256) void per_class_kernel(
    const u32* __restrict__ scoreT,
    const float* __restrict__ roi,      // (N,4)
    const float* __restrict__ deltas,   // (N, L*4)
    u64* __restrict__ cand_key,         // (L*CAP)
    float4* __restrict__ cand_box,      // (L*CAP)
    u64* __restrict__ fb_key,           // (L)
    float4* __restrict__ fb_box)        // (L)
{
    const int cls = blockIdx.x;
    const int t = threadIdx.x;

    __shared__ char sm[SMEM_B];
    __shared__ int sCnt, sK;
    __shared__ u64 sGmax;
    __shared__ u64 keepm[NCH];
    __shared__ int wtot[4];

    u64* skey  = (u64*)sm;
    u64* skey2 = (u64*)(sm + 16384);
    int* histR  = (int*)(sm + 32768);
    int* cursor = (int*)(sm + 36864);
    int* dstart = (int*)(sm + 40960);

    if (t == 0) { sCnt = 0; sK = 0; sGmax = 0ull; }
    for (int s = t; s < CAP; s += 256) cand_key[cls * CAP + s] = 0ull;
    for (int i = t; i < NBK; i += 256) histR[i] = 0;
    __syncthreads();

    // B1: load score bits (coalesced 8 KB), compact > 0.5, track max
    u64 lq[8];
    int ln = 0;
    u64 lmax = 0ull;
    for (int i = t; i < NN; i += 256) {
        u32 s = scoreT[cls * NN + i];
        u64 key = ((u64)s << 32) | (u32)(~(u32)i);
        if (key > lmax) lmax = key;
        if (s > 0x3F000000u) lq[ln++] = key;   // bits>0.5-bits <=> score>0.5 (positive)
    }
    atomicMax(&sGmax, lmax);
    int wbase = atomicAdd(&sCnt, ln);
    for (int j = 0; j < ln; ++j) skey[wbase + j] = lq[j];
    __syncthreads();
    const int M = sCnt;

    // per-class fallback rank-0 box (always kept by NMS)
    if (t == 0) {
        u64 g = sGmax;
        u32 a0 = ~(u32)(g & 0xFFFFFFFFull);
        float4 rb = *(const float4*)(roi + a0 * 4);
        float4 dd = *(const float4*)(deltas + a0 * (LL * 4) + cls * 4);
        fb_box[cls] = decode_box(rb, dd);
        fb_key[cls] = (g & 0xFFFFFFFF00000000ull) | (u32)(~(u32)(cls * NN));
    }

    // B2: exact bucket sort desc (keys unique; ties broken by low bits in insertion)
    for (int i = t; i < M; i += 256) atomicAdd(&histR[rb_of(skey[i])], 1);
    __syncthreads();
    desc_scan(histR, dstart, cursor, wtot, t);
    for (int i = t; i < M; i += 256) {
        u64 k = skey[i];
        int pos = atomicAdd(&cursor[rb_of(k)], 1);
        skey2[pos] = k;
    }
    __syncthreads();
    for (int rb = t; rb < NBK; rb += 256) {
        int s = dstart[rb], len = histR[rb];
        for (int a = s + 1; a < s + len; ++a) {   // insertion sort desc (avg len ~1)
            u64 v = skey2[a];
            int b = a;
            while (b > s && skey2[b - 1] < v) { skey2[b] = skey2[b - 1]; --b; }
            skey2[b] = v;
        }
    }
    __syncthreads();   // skey region dead -> reuse for NMS arena

    float4* cbox = (float4*)sm;                 // [TMAX]
    u64* R  = (u64*)(sm + 5120);                // [NCH*64]
    u64* Tm = (u64*)(sm + 7680);                // [10*64]
    float4* kept = (float4*)(sm + 12800);       // [CAP]

    const int TT = min(M, TMAX);
    const int NCHe = (TT + 63) / 64;
    const int NJ = NCHe * (NCHe + 1) / 2;       // jobs: (cj,ci) ci<=cj

    // B3: decode top-TT (gathers)
    for (int r = t; r < TT; r += 256) {
        u32 a = ~(u32)(skey2[r] & 0xFFFFFFFFull);
        float4 rbx = *(const float4*)(roi + a * 4);
        float4 dd = *(const float4*)(deltas + a * (LL * 4) + cls * 4);
        cbox[r] = decode_box(rbx, dd);
    }
    __syncthreads();

    // B4: pair-bit matrix, balanced lane-tasks (64 per job, strided over 256 thr)
    for (int task = t; task < NJ * 64; task += 256) {
        const int jobid = task >> 6, j = task & 63;
        int cj = 0, acc = 0;
        while (acc + cj + 1 <= jobid) { acc += cj + 1; ++cj; }
        const int ci = jobid - acc;
        const int gj = cj * 64 + j;
        const int nbj = min(64, TT - cj * 64);
        if (ci == cj) {
            u64 row = 0ull;
            if (j < nbj) {
                float4 bj = cbox[gj];
                for (int r2 = j + 1; r2 < nbj; ++r2)
                    if (iou_gt(bj, cbox[cj * 64 + r2])) row |= (1ull << r2);
            }
            R[cj * 64 + j] = row;
        } else {
            u64 wd = 0ull;
            if (j < nbj) {
                float4 bj = cbox[gj];
                const float4* cb = cbox + ci * 64;   // same addr across lanes: broadcast
                for (int i = 0; i < 64; ++i)
                    if (iou_gt(cb[i], bj)) wd |= (1ull << i);
            }
            Tm[(cj * (cj - 1) / 2 + ci) * 64 + j] = wd;
        }
    }
    __syncthreads();

    // B5: wave0 barrier-free resolve with sparse skip (overlaps are rare)
    if (t < 64) {
        int K = 0;
        for (int cj = 0; cj < NCHe; ++cj) {
            if (K >= CAP) break;
            const int nb = min(64, TT - cj * 64);
            u64 row = R[cj * 64 + t];
            bool ext = (t >= nb);
            for (int ci = 0; ci < cj; ++ci)
                if (Tm[(cj * (cj - 1) / 2 + ci) * 64 + t] & keepm[ci]) ext = true;
            u64 rem = __ballot(ext);
            const u64 nz = __ballot(row != 0ull) & ~rem;
            u64 m = nz;
            while (m) {
                int i = __ffsll(m) - 1;
                u64 ri = shfl_u64(row, i);
                rem |= ri;
                u64 gt = (i == 63) ? 0ull : ~lowmask(i + 1);
                m = nz & ~rem & gt;
            }
            u64 keep = ~rem & lowmask(nb);
            if (t == 0) keepm[cj] = keep;
            if (t < nb && ((keep >> t) & 1ull)) {
                int krank = K + __popcll(keep & lowmask(t));
                if (krank < CAP) {
                    kept[krank] = cbox[cj * 64 + t];
                    int slot = cls * CAP + krank;
                    // low bits ~slot: slot order isomorphic to flat-index order ->
                    // reproduces lax.top_k stable tie-break
                    cand_key[slot] = (skey2[cj * 64 + t] & 0xFFFFFFFF00000000ull) |
                                     (u32)(~(u32)slot);
                    cand_box[slot] = cbox[cj * 64 + t];
                }
            }
            K += __popcll(keep);
        }
        if (t == 0) sK = K;
    }
    __syncthreads();

    // B6: rare exact continuation past TMAX (chunked, R2-style)
    int K = sK;
    if (K < CAP && M > TT) {
        u64* sup = (u64*)(sm + 5120);               // reuse R: [4][64]
        unsigned char* extq = (unsigned char*)(sm + 7680);   // reuse Tm: [4][64]
        const int q = t >> 6, r = t & 63;
        for (int base = TT; base < M; base += 64) {
            K = sK;
            if (K >= CAP) break;
            const int nb = min(64, M - base);
            if (t < nb) {
                u32 a = ~(u32)(skey2[base + t] & 0xFFFFFFFFull);
                float4 rbx = *(const float4*)(roi + a * 4);
                float4 dd = *(const float4*)(deltas + a * (LL * 4) + cls * 4);
                cbox[t] = decode_box(rbx, dd);
            }
            __syncthreads();
            u64 bits = 0ull;
            if (r < nb) {
                float4 br = cbox[r];
                int lo = max(r + 1, q * 16), hi = min(nb, (q + 1) * 16);
                for (int r2 = lo; r2 < hi; ++r2)
                    if (iou_gt(br, cbox[r2])) bits |= (1ull << r2);
            }
            sup[q * 64 + r] = bits;
            bool f = false;
            if (r < nb) {
                float4 bm = cbox[r];
                int per = (K + 3) >> 2;
                int e0 = q * per, e1 = min(K, e0 + per);
                for (int e = e0; e < e1; ++e)
                    if (iou_gt(kept[e], bm)) { f = true; break; }
            }
            extq[q * 64 + r] = f ? 1 : 0;
            __syncthreads();
            if (t < 64) {
                u64 row = sup[t] | sup[64 + t] | sup[128 + t] | sup[192 + t];
                bool ext = (t < nb) ? ((extq[t] | extq[64 + t] | extq[128 + t] |
                                        extq[192 + t]) != 0) : true;
                u64 rem = __ballot(ext);
                const u64 nz = __ballot(row != 0ull) & ~rem;
                u64 m = nz;
                while (m) {
                    int i = __ffsll(m) - 1;
                    u64 ri = shfl_u64(row, i);
                    rem |= ri;
                    u64 gt = (i == 63) ? 0ull : ~lowmask(i + 1);
                    m = nz & ~rem & gt;
                }
                u64 keep = ~rem & lowmask(nb);
                if (t < nb && ((keep >> t) & 1ull)) {
                    int krank = K + __popcll(keep & lowmask(t));
                    if (krank < CAP) {
                        kept[krank] = cbox[t];
                        int slot = cls * CAP + krank;
                        cand_key[slot] = (skey2[base + t] & 0xFFFFFFFF00000000ull) |
                                         (u32)(~(u32)slot);
                        cand_box[slot] = cbox[t];
                    }
                }
                if (t == 0) sK = K + __popcll(keep);
            }
            __syncthreads();
        }
    }
}

// ---------------- Kernel C: global top-200 via bucket threshold ----------------
#define SMEM_C 54080
__global__ __launch_bounds__(256) void topk_kernel(
    const u64* __restrict__ cand_key,
    const float4* __restrict__ cand_box,
    const u64* __restrict__ fb_key,
    const float4* __restrict__ fb_box,
    float* __restrict__ out)   // [800 boxes][200 labels][200 scores]
{
    const int t = threadIdx.x;
    __shared__ char sm[SMEM_C];
    __shared__ int wtot[4];
    __shared__ int sRbstar;

    u64* keys   = (u64*)sm;                     // [TOT]
    int* histR  = (int*)(sm + 33600);
    int* cursor = (int*)(sm + 37696);
    int* dstart = (int*)(sm + 41792);
    u64* arr    = (u64*)(sm + 45888);           // [1024]

    for (int i = t; i < NBK; i += 256) histR[i] = 0;
    for (int i = t; i < 1024; i += 256) arr[i] = 0ull;
    if (t == 0) sRbstar = 1023;
    __syncthreads();

    for (int i = t; i < TOT; i += 256) {
        u64 k = cand_key[i];
        keys[i] = k;
        if (k != 0ull) atomicAdd(&histR[rb_of(k)], 1);
    }
    __syncthreads();
    desc_scan(histR, dstart, cursor, wtot, t);
    for (int k = 0; k < 4; ++k) {
        int rb = 4 * t + k;
        if (dstart[rb] + histR[rb] >= CAP) atomicMin(&sRbstar, rb);
    }
    __syncthreads();
    const int rbstar = sRbstar;
    for (int i = t; i < TOT; i += 256) {
        u64 k = keys[i];
        if (k != 0ull) {
            int rb = rb_of(k);
            if (rb <= rbstar) {
                int pos = atomicAdd(&cursor[rb], 1);
                if (pos < 1024) arr[pos] = k;
            }
        }
    }
    __syncthreads();
    for (int rb = t; rb <= rbstar; rb += 256) {
        int s = dstart[rb], len = histR[rb];
        int e = min(s + len, 1024);
        for (int a = s + 1; a < e; ++a) {
            u64 v = arr[a];
            int b = a;
            while (b > s && arr[b - 1] < v) { arr[b] = arr[b - 1]; --b; }
            arr[b] = v;
        }
    }
    __syncthreads();

    for (int o = t; o < CAP; o += 256) {
        u64 key = arr[o];
        float4 b = make_float4(0.0f, 0.0f, 0.0f, 0.0f);
        float lab = 0.0f, sc = 0.0f;
        if (key != 0ull) {   // all candidates have score > 0.5 -> valid
            u32 slot = ~(u32)(key & 0xFFFFFFFFull);
            sc = __uint_as_float((u32)(key >> 32));
            lab = (float)(slot / CAP);
            b = clip01(cand_box[slot]);
        }
        out[o * 4 + 0] = b.x;
        out[o * 4 + 1] = b.y;
        out[o * 4 + 2] = b.z;
        out[o * 4 + 3] = b.w;
        out[4 * CAP + o] = lab;
        out[5 * CAP + o] = sc;
    }
    __syncthreads();

    // fallback: no candidate anywhere -> global best kept box at slot 0
    if (t == 0 && arr[0] == 0ull) {
        u64 best = 0ull;
        int bc = 0;
        for (int c = 0; c < LL; ++c) {
            u64 k = fb_key[c];
            if (k > best) { best = k; bc = c; }
        }
        float bs = __uint_as_float((u32)(best >> 32));
        if (bs >= 0.001f) {
            float4 bb = clip01(fb_box[bc]);
            out[0] = bb.x; out[1] = bb.y; out[2] = bb.z; out[3] = bb.w;
            out[4 * CAP] = (float)bc;
            out[5 * CAP] = bs;
        }
    }
}

extern "C" void kernel_launch(void* const* d_in, const int* in_sizes, int n_in,
                              void* d_out, int out_size, void* d_ws, size_t ws_size,
                              hipStream_t stream) {
    const float* roi    = (const float*)d_in[0];   // (1,2048,4)
    const float* deltas = (const float*)d_in[1];   // (1,2048,84)
    const float* probs  = (const float*)d_in[2];   // (1,2048,21)
    float* out = (float*)d_out;

    char* ws = (char*)d_ws;
    u32*    scoreT   = (u32*)ws;                   // 21*2048*4 = 172032
    u64*    cand_key = (u64*)(ws + 172032);        // 4200*8   = 33600 -> 205632
    float4* cand_box = (float4*)(ws + 205632);     // 4200*16  = 67200 -> 272832 (16B aligned)
    u64*    fb_key   = (u64*)(ws + 272832);        // 168 -> 273000
    float4* fb_box   = (float4*)(ws + 273008);     // 336 -> 273344 (16B aligned)

    score_kernel<<<NN / 256, 256, 0, stream>>>(probs, scoreT);
    per_class_kernel<<<LL, 256, 0, stream>>>(scoreT, roi, deltas,
                                             cand_key, cand_box, fb_key, fb_box);
    topk_kernel<<<1, 256, 0, stream>>>(cand_key, cand_box, fb_key, fb_box, out);
}

// Round 5
// 93.658 us; speedup vs baseline: 1.8861x; 1.6025x over previous
//
#include <hip/hip_runtime.h>
#include <stdint.h>

#define NN 2048
#define LL 21
#define CAP 200
#define TOT (LL * CAP)
#define TMAX 320                 // matrix-resolve candidate window (5 chunks of 64)
#define NCH (TMAX / 64)
#define NBK 1024                 // score buckets
#define ARRCAP 1200

typedef unsigned long long u64;
typedef unsigned int u32;

__device__ __forceinline__ u64 shfl_u64(u64 v, int lane) {
    int lo = (int)(u32)(v & 0xFFFFFFFFull);
    int hi = (int)(u32)(v >> 32);
    lo = __shfl(lo, lane);
    hi = __shfl(hi, lane);
    return ((u64)(u32)hi << 32) | (u32)lo;
}

__device__ __forceinline__ u64 shfl_xor_u64(u64 v, int mask) {
    int lo = (int)(u32)(v & 0xFFFFFFFFull);
    int hi = (int)(u32)(v >> 32);
    lo = __shfl_xor(lo, mask);
    hi = __shfl_xor(hi, mask);
    return ((u64)(u32)hi << 32) | (u32)lo;
}

__device__ __forceinline__ float4 clip01(float4 b) {
    b.x = fminf(fmaxf(b.x, 0.0f), 1.0f);
    b.y = fminf(fmaxf(b.y, 0.0f), 1.0f);
    b.z = fminf(fmaxf(b.z, 0.0f), 1.0f);
    b.w = fminf(fmaxf(b.w, 0.0f), 1.0f);
    return b;
}

// decode, exact np op order (absmax 0.0 in R1-R4)
__device__ __forceinline__ float4 decode_box(const float4 roi, const float4 dd) {
#pragma clang fp contract(off)
    float h  = roi.z - roi.x;
    float w  = roi.w - roi.y;
    float cy = roi.x + 0.5f * h;
    float cx = roi.y + 0.5f * w;
    float d0 = dd.x * 0.1f;
    float d1 = dd.y * 0.1f;
    float d2 = dd.z * 0.2f;
    float d3 = dd.w * 0.2f;
    float nh = (float)exp((double)d2) * h;
    float nw = (float)exp((double)d3) * w;
    float ncy = d0 * h + cy;
    float ncx = d1 * w + cx;
    return make_float4(ncy - 0.5f * nh, ncx - 0.5f * nw, ncy + 0.5f * nh, ncx + 0.5f * nw);
}

__device__ __forceinline__ bool iou_gt(const float4 a, const float4 b) {
#pragma clang fp contract(off)
    float areaA = (a.z - a.x) * (a.w - a.y);
    float areaB = (b.z - b.x) * (b.w - b.y);
    float ih = fminf(a.z, b.z) - fmaxf(a.x, b.x);
    ih = fmaxf(ih, 0.0f);
    float iw = fminf(a.w, b.w) - fmaxf(a.y, b.y);
    iw = fmaxf(iw, 0.0f);
    float inter = ih * iw;
    float denom = ((areaA + areaB) - inter) + 1e-9f;
    return (inter / denom) > 0.5f;
}

// reverse-bucket: rb=0 is the HIGHEST score bucket (descending order)
__device__ __forceinline__ int rb_of(u64 key) {
    u32 sb = (u32)(key >> 32);                 // score bits in (0x3F000000, 0x3F800000)
    int rb = 1023 - (int)((sb - 0x3F000000u) >> 13);
    return min(max(rb, 0), 1023);
}

__device__ __forceinline__ u64 lowmask(int n) {
    return (n >= 64) ? ~0ull : ((1ull << n) - 1ull);
}

// descending exclusive scan of histR[1024] -> dstart & cursor; nthr in {256,512}
__device__ __forceinline__ void desc_scan(int* histR, int* dstart, int* cursor,
                                          int* wtot, int t, int nthr) {
    const int PB = NBK / nthr;
    const int lane = t & 63, w = t >> 6;
    int c[4], local = 0;
    for (int k = 0; k < PB; ++k) { c[k] = histR[PB * t + k]; local += c[k]; }
    int incl = local;
    for (int d = 1; d < 64; d <<= 1) {
        int v = __shfl_up(incl, d);
        if (lane >= d) incl += v;
    }
    if (lane == 63) wtot[w] = incl;
    __syncthreads();
    int woff = 0;
    for (int i = 0; i < w; ++i) woff += wtot[i];
    int run = woff + incl - local;
    for (int k = 0; k < PB; ++k) {
        dstart[PB * t + k] = run;
        cursor[PB * t + k] = run;
        run += c[k];
    }
    __syncthreads();
}

// ---------------- Kernel A: grid-parallel argmax + score bits ----------------
__global__ __launch_bounds__(256) void score_kernel(
    const float* __restrict__ probs,   // (N, L)
    u32* __restrict__ scoreT)          // (L, N) score bits (0 if background)
{
    __shared__ float tile[256 * LL];
    const int a0 = blockIdx.x * 256;
    const int t = threadIdx.x;
    const float4* src = (const float4*)probs + blockIdx.x * 1344;
    float4* dst = (float4*)tile;
    for (int i = t; i < 1344; i += 256) dst[i] = src[i];
    __syncthreads();
    const float* row = tile + t * LL;   // stride 21 (odd): 2-way max, free
    float best = row[0];
    int bi = 0;
    for (int j = 1; j < LL; ++j) {
        float v = row[j];
        if (v > best) { best = v; bi = j; }
    }
    for (int c = 0; c < LL; ++c)
        scoreT[c * NN + a0 + t] = (bi != 0) ? __float_as_uint(row[c]) : 0u;  // coalesced
}

// ---------------- Kernel B: per-class sort + matrix NMS (512 threads) --------
// Arena layout:
// [0,16384)      skey (compacted raw)  -> skey3 (final sorted, after scatter)
// [16384,32768)  skey2 (bucket-grouped) -> NMS arena after sort:
//                cbox@+0(5120) R@+5120(2560) Tm@+7680(5120) kept@+12800(3200)
//                B6 reuse: sup@+5120(4096) extq@+9216(512)
// [32768,45056)  histR / cursor / dstart
#define SMEM_B 45056
#define NBASE 16384

__global__ __launch_bounds__(512) void per_class_kernel(
    const u32* __restrict__ scoreT,
    const float* __restrict__ roi,      // (N,4)
    const float* __restrict__ deltas,   // (N, L*4)
    u64* __restrict__ cand_key,         // (L*CAP)
    float4* __restrict__ cand_box,      // (L*CAP)
    u64* __restrict__ fb_key,           // (L)
    float4* __restrict__ fb_box)        // (L)
{
    const int cls = blockIdx.x;
    const int t = threadIdx.x;
    const int lane = t & 63;

    __shared__ char sm[SMEM_B];
    __shared__ int sCnt, sK;
    __shared__ u64 sGmax;
    __shared__ u64 keepm[NCH];
    __shared__ int wtot[8];

    u64* skey  = (u64*)sm;
    u64* skey3 = (u64*)sm;                  // overwrites skey after it's consumed
    u64* skey2 = (u64*)(sm + NBASE);
    int* histR  = (int*)(sm + 32768);
    int* cursor = (int*)(sm + 36864);
    int* dstart = (int*)(sm + 40960);

    if (t == 0) { sCnt = 0; sK = 0; sGmax = 0ull; }
    for (int s = t; s < CAP; s += 512) cand_key[cls * CAP + s] = 0ull;
    for (int i = t; i < NBK; i += 512) histR[i] = 0;
    __syncthreads();

    // B1: vector load (uint4 covers all 2048 anchors in one pass), compact > 0.5
    uint4 s4 = ((const uint4*)(scoreT + cls * NN))[t];
    u32 sv[4] = { s4.x, s4.y, s4.z, s4.w };
    u64 lq[4];
    int ln = 0;
    u64 lmax = 0ull;
    for (int k = 0; k < 4; ++k) {
        u32 a = 4 * t + k;
        u64 key = ((u64)sv[k] << 32) | (u32)(~a);
        if (key > lmax) lmax = key;
        if (sv[k] > 0x3F000000u) lq[ln++] = key;   // strict score > 0.5
    }
    // wave max-reduce then 1 atomic per wave (no 512-way storm)
    for (int d = 1; d < 64; d <<= 1) {
        u64 o = shfl_xor_u64(lmax, d);
        if (o > lmax) lmax = o;
    }
    if (lane == 0) atomicMax(&sGmax, lmax);
    // wave scan of ln -> 1 atomicAdd per wave
    int incl = ln;
    for (int d = 1; d < 64; d <<= 1) {
        int v = __shfl_up(incl, d);
        if (lane >= d) incl += v;
    }
    int wsum = __shfl(incl, 63);
    int wbase = 0;
    if (lane == 63) wbase = atomicAdd(&sCnt, wsum);
    wbase = __shfl(wbase, 63);
    int off = wbase + incl - ln;
    for (int j = 0; j < ln; ++j) skey[off + j] = lq[j];
    __syncthreads();
    const int M = sCnt;

    // per-class fallback rank-0 box (always kept by NMS)
    if (t == 0) {
        u64 g = sGmax;
        u32 a0 = ~(u32)(g & 0xFFFFFFFFull);
        float4 rb = *(const float4*)(roi + a0 * 4);
        float4 dd = *(const float4*)(deltas + a0 * (LL * 4) + cls * 4);
        fb_box[cls] = decode_box(rb, dd);
        fb_key[cls] = (g & 0xFFFFFFFF00000000ull) | (u32)(~(u32)(cls * NN));
    }

    // B2: bucket histogram + scan + scatter + rank-by-count (no serial chains)
    for (int i = t; i < M; i += 512) atomicAdd(&histR[rb_of(skey[i])], 1);
    __syncthreads();
    desc_scan(histR, dstart, cursor, wtot, t, 512);
    for (int i = t; i < M; i += 512) {
        u64 k = skey[i];
        int pos = atomicAdd(&cursor[rb_of(k)], 1);
        skey2[pos] = k;
    }
    __syncthreads();   // skey consumed -> region becomes skey3
    for (int p = t; p < M; p += 512) {
        u64 k = skey2[p];
        int rb = rb_of(k);
        int s = dstart[rb], e = s + histR[rb];
        int rnk = s;
        for (int q = s; q < e; ++q) rnk += (skey2[q] > k) ? 1 : 0;  // independent reads
        skey3[rnk] = k;
    }
    __syncthreads();   // skey2 dead -> NMS arena

    float4* cbox = (float4*)(sm + NBASE);            // [TMAX]
    u64* R  = (u64*)(sm + NBASE + 5120);             // [NCH*64]
    u64* Tm = (u64*)(sm + NBASE + 7680);             // [10*64]
    float4* kept = (float4*)(sm + NBASE + 12800);    // [CAP]

    const int TT = min(M, TMAX);
    const int NCHe = (TT + 63) / 64;
    const int NJ = NCHe * (NCHe + 1) / 2;            // jobs (cj,ci) ci<=cj

    // B3: decode top-TT
    for (int r = t; r < TT; r += 512) {
        u32 a = ~(u32)(skey3[r] & 0xFFFFFFFFull);
        float4 rbx = *(const float4*)(roi + a * 4);
        float4 dd = *(const float4*)(deltas + a * (LL * 4) + cls * 4);
        cbox[r] = decode_box(rbx, dd);
    }
    __syncthreads();

    // B4: pair-bit matrix, balanced lane-tasks
    for (int task = t; task < NJ * 64; task += 512) {
        const int jobid = task >> 6, j = task & 63;
        int cj = 0, acc = 0;
        while (acc + cj + 1 <= jobid) { acc += cj + 1; ++cj; }
        const int ci = jobid - acc;
        const int gj = cj * 64 + j;
        const int nbj = min(64, TT - cj * 64);
        if (ci == cj) {
            u64 row = 0ull;
            if (j < nbj) {
                float4 bj = cbox[gj];
                for (int r2 = j + 1; r2 < nbj; ++r2)
                    if (iou_gt(bj, cbox[cj * 64 + r2])) row |= (1ull << r2);
            }
            R[cj * 64 + j] = row;
        } else {
            u64 wd = 0ull;
            if (j < nbj) {
                float4 bj = cbox[gj];
                const float4* cb = cbox + ci * 64;   // broadcast reads
                for (int i = 0; i < 64; ++i)
                    if (iou_gt(cb[i], bj)) wd |= (1ull << i);
            }
            Tm[(cj * (cj - 1) / 2 + ci) * 64 + j] = wd;
        }
    }
    __syncthreads();

    // B5: wave0 barrier-free resolve with sparse skip (overlaps rare)
    if (t < 64) {
        int K = 0;
        for (int cj = 0; cj < NCHe; ++cj) {
            if (K >= CAP) break;
            const int nb = min(64, TT - cj * 64);
            u64 row = R[cj * 64 + t];
            bool ext = (t >= nb);
            for (int ci = 0; ci < cj; ++ci)
                if (Tm[(cj * (cj - 1) / 2 + ci) * 64 + t] & keepm[ci]) ext = true;
            u64 rem = __ballot(ext);
            const u64 nz = __ballot(row != 0ull) & ~rem;
            u64 m = nz;
            while (m) {
                int i = __ffsll(m) - 1;
                u64 ri = shfl_u64(row, i);
                rem |= ri;
                u64 gt = (i == 63) ? 0ull : ~lowmask(i + 1);
                m = nz & ~rem & gt;
            }
            u64 keep = ~rem & lowmask(nb);
            if (t == 0) keepm[cj] = keep;
            if (t < nb && ((keep >> t) & 1ull)) {
                int krank = K + __popcll(keep & lowmask(t));
                if (krank < CAP) {
                    kept[krank] = cbox[cj * 64 + t];
                    int slot = cls * CAP + krank;
                    // ~slot low bits: slot order isomorphic to flat-index order ->
                    // reproduces lax.top_k stable tie-break
                    cand_key[slot] = (skey3[cj * 64 + t] & 0xFFFFFFFF00000000ull) |
                                     (u32)(~(u32)slot);
                    cand_box[slot] = cbox[cj * 64 + t];
                }
            }
            K += __popcll(keep);
        }
        if (t == 0) sK = K;
    }
    __syncthreads();

    // B6: rare exact continuation past TMAX (8 groups of 64)
    int K = sK;
    if (K < CAP && M > TT) {
        u64* sup = (u64*)(sm + NBASE + 5120);               // [8][64]
        unsigned char* extq = (unsigned char*)(sm + NBASE + 9216);  // [8][64]
        const int g = t >> 6, r = t & 63;
        for (int base = TT; base < M; base += 64) {
            K = sK;
            if (K >= CAP) break;
            const int nb = min(64, M - base);
            if (t < nb) {
                u32 a = ~(u32)(skey3[base + t] & 0xFFFFFFFFull);
                float4 rbx = *(const float4*)(roi + a * 4);
                float4 dd = *(const float4*)(deltas + a * (LL * 4) + cls * 4);
                cbox[t] = decode_box(rbx, dd);
            }
            __syncthreads();
            u64 bits = 0ull;
            if (r < nb) {
                float4 br = cbox[r];
                int lo = max(r + 1, g * 8), hi = min(nb, (g + 1) * 8);
                for (int r2 = lo; r2 < hi; ++r2)
                    if (iou_gt(br, cbox[r2])) bits |= (1ull << r2);
            }
            sup[g * 64 + r] = bits;
            bool f = false;
            if (r < nb) {
                float4 bm = cbox[r];
                int per = (K + 7) >> 3;
                int e0 = g * per, e1 = min(K, e0 + per);
                for (int e = e0; e < e1; ++e)
                    if (iou_gt(kept[e], bm)) { f = true; break; }
            }
            extq[g * 64 + r] = f ? 1 : 0;
            __syncthreads();
            if (t < 64) {
                u64 row = 0ull;
                int extv = 0;
                for (int j = 0; j < 8; ++j) { row |= sup[j * 64 + t]; extv |= extq[j * 64 + t]; }
                bool ext = (t < nb) ? (extv != 0) : true;
                u64 rem = __ballot(ext);
                const u64 nz = __ballot(row != 0ull) & ~rem;
                u64 m = nz;
                while (m) {
                    int i = __ffsll(m) - 1;
                    u64 ri = shfl_u64(row, i);
                    rem |= ri;
                    u64 gt = (i == 63) ? 0ull : ~lowmask(i + 1);
                    m = nz & ~rem & gt;
                }
                u64 keep = ~rem & lowmask(nb);
                if (t < nb && ((keep >> t) & 1ull)) {
                    int krank = K + __popcll(keep & lowmask(t));
                    if (krank < CAP) {
                        kept[krank] = cbox[t];
                        int slot = cls * CAP + krank;
                        cand_key[slot] = (skey3[base + t] & 0xFFFFFFFF00000000ull) |
                                         (u32)(~(u32)slot);
                        cand_box[slot] = cbox[t];
                    }
                }
                if (t == 0) sK = K + __popcll(keep);
            }
            __syncthreads();
        }
    }
}

// ---------------- Kernel C: global top-200, chain-free ----------------
__global__ __launch_bounds__(256) void topk_kernel(
    const u64* __restrict__ cand_key,
    const float4* __restrict__ cand_box,
    const u64* __restrict__ fb_key,
    const float4* __restrict__ fb_box,
    float* __restrict__ out)   // [800 boxes][200 labels][200 scores]
{
    const int t = threadIdx.x;
    __shared__ u64 keys[TOT];
    __shared__ int histR[NBK], cursor[NBK], dstart[NBK];
    __shared__ u64 arr[ARRCAP];
    __shared__ u64 outk[CAP];
    __shared__ int wtot[8];
    __shared__ int sRbstar;

    for (int i = t; i < NBK; i += 256) histR[i] = 0;
    for (int i = t; i < CAP; i += 256) outk[i] = 0ull;
    if (t == 0) sRbstar = NBK - 1;
    __syncthreads();

    // load 4200 keys as ulong2 (independent, pipelined) + histogram
    const ulong2* ck2 = (const ulong2*)cand_key;
    for (int i = t; i < TOT / 2; i += 256) {
        ulong2 k2 = ck2[i];
        keys[2 * i]     = k2.x;
        keys[2 * i + 1] = k2.y;
        if (k2.x != 0ull) atomicAdd(&histR[rb_of(k2.x)], 1);
        if (k2.y != 0ull) atomicAdd(&histR[rb_of(k2.y)], 1);
    }
    __syncthreads();
    desc_scan(histR, dstart, cursor, wtot, t, 256);
    // unique crossing bucket: dstart < CAP <= dstart+len (single writer, no storm)
    for (int k = 0; k < 4; ++k) {
        int rb = 4 * t + k;
        if (dstart[rb] < CAP && dstart[rb] + histR[rb] >= CAP) sRbstar = rb;
    }
    __syncthreads();
    const int rbstar = sRbstar;

    // scatter candidates in buckets <= rbstar (bucket-grouped, order-agnostic)
    for (int i = t; i < TOT; i += 256) {
        u64 k = keys[i];
        if (k != 0ull) {
            int rb = rb_of(k);
            if (rb <= rbstar) {
                int pos = atomicAdd(&cursor[rb], 1);
                if (pos < ARRCAP) arr[pos] = k;
            }
        }
    }
    __syncthreads();

    // rank-by-count within buckets: exact global rank, direct scatter to outk
    const int E = min(dstart[rbstar] + histR[rbstar], ARRCAP);
    for (int p = t; p < E; p += 256) {
        u64 k = arr[p];
        int rb = rb_of(k);
        int s = dstart[rb], e = min(s + histR[rb], ARRCAP);
        int rnk = s;
        for (int q = s; q < e; ++q) rnk += (arr[q] > k) ? 1 : 0;  // independent reads
        if (rnk < CAP) outk[rnk] = k;
    }
    __syncthreads();

    for (int o = t; o < CAP; o += 256) {
        u64 key = outk[o];
        float4 b = make_float4(0.0f, 0.0f, 0.0f, 0.0f);
        float lab = 0.0f, sc = 0.0f;
        if (key != 0ull) {   // all candidates have score > 0.5 -> valid
            u32 slot = ~(u32)(key & 0xFFFFFFFFull);
            sc = __uint_as_float((u32)(key >> 32));
            lab = (float)(slot / CAP);
            b = clip01(cand_box[slot]);
        }
        out[o * 4 + 0] = b.x;
        out[o * 4 + 1] = b.y;
        out[o * 4 + 2] = b.z;
        out[o * 4 + 3] = b.w;
        out[4 * CAP + o] = lab;
        out[5 * CAP + o] = sc;
    }
    __syncthreads();

    // fallback: no candidate anywhere -> global best kept box at slot 0
    if (t == 0 && outk[0] == 0ull) {
        u64 best = 0ull;
        int bc = 0;
        for (int c = 0; c < LL; ++c) {
            u64 k = fb_key[c];
            if (k > best) { best = k; bc = c; }
        }
        float bs = __uint_as_float((u32)(best >> 32));
        if (bs >= 0.001f) {
            float4 bb = clip01(fb_box[bc]);
            out[0] = bb.x; out[1] = bb.y; out[2] = bb.z; out[3] = bb.w;
            out[4 * CAP] = (float)bc;
            out[5 * CAP] = bs;
        }
    }
}

extern "C" void kernel_launch(void* const* d_in, const int* in_sizes, int n_in,
                              void* d_out, int out_size, void* d_ws, size_t ws_size,
                              hipStream_t stream) {
    const float* roi    = (const float*)d_in[0];   // (1,2048,4)
    const float* deltas = (const float*)d_in[1];   // (1,2048,84)
    const float* probs  = (const float*)d_in[2];   // (1,2048,21)
    float* out = (float*)d_out;

    char* ws = (char*)d_ws;
    u32*    scoreT   = (u32*)ws;                   // 21*2048*4 = 172032
    u64*    cand_key = (u64*)(ws + 172032);        // 4200*8   = 33600 -> 205632
    float4* cand_box = (float4*)(ws + 205632);     // 4200*16  = 67200 -> 272832
    u64*    fb_key   = (u64*)(ws + 272832);        // 168 -> 273000
    float4* fb_box   = (float4*)(ws + 273008);     // 336 -> 273344

    score_kernel<<<NN / 256, 256, 0, stream>>>(probs, scoreT);
    per_class_kernel<<<LL, 512, 0, stream>>>(scoreT, roi, deltas,
                                             cand_key, cand_box, fb_key, fb_box);
    topk_kernel<<<1, 256, 0, stream>>>(cand_key, cand_box, fb_key, fb_box, out);
}